// Round 7
// baseline (684.164 us; speedup 1.0000x reference)
//
#include <hip/hip_runtime.h>

// Problem constants (from reference)
#define NUu 200000
#define NIi 100000
#define EE  600000
// D = H = 128

#define SCAP 768      // LDS src-index window (block windows avg 192/384; global fallback covers)
#define NB_USER 3125  // (NUu+63)/64
#define NB_ITEM 1563  // (NIi+63)/64

#define EB2 586       // ceil(EE/1024) edge blocks
#define NBIN 512      // MSD buckets: bin = dst>>9 (512 nodes per bucket)
#define BINS_U 391    // ceil(200000/512)
#define BINS_I 196    // ceil(100000/512)

// prep1 grid sections (hist + weights + bias + conv fused; overlap in one launch)
#define PB_HIST 586       // [0,586) user-dst hist | [586,1172) item-dst hist
#define PB_W0   1172      // [1172,1428) fused weights
#define PB_B0   1428      // {1428} fused bias
#define PB_CU0  1429      // [1429,13929) x_user->bf16
#define PB_CI0  13929     // [13929,20179) x_item->bf16
#define PB_END  20179

typedef short short8 __attribute__((ext_vector_type(8)));
typedef float floatx4 __attribute__((ext_vector_type(4)));

// float -> bf16 bits, round-to-nearest-even
__device__ __forceinline__ unsigned short f2bf(float f) {
  union { float f; unsigned int u; } v; v.f = f;
  unsigned int r = v.u + 0x7FFFu + ((v.u >> 16) & 1u);
  return (unsigned short)(r >> 16);
}
// bf16 pair (packed in u32) -> f32
__device__ __forceinline__ float bflo(unsigned int u) { return __uint_as_float(u << 16); }
__device__ __forceinline__ float bfhi(unsigned int u) { return __uint_as_float(u & 0xFFFF0000u); }

// ---------------------------------------------------------------------------
// prep1: MSD histogram (LDS only, NO global atomics) + weights + bias + conv.
//   [0,1172)   per-1024-edge-block 512-bin hist of dst>>9 -> bh[bin*EB2+block]
//   [1172,1428) fused weights W1=Wl@W2, W2=Wr@W2 -> bf16 MFMA B-frag layout
//   {1428}     fused bias bl@W2 + b2
//   [1429,...) x -> bf16 conversion
// ---------------------------------------------------------------------------
__global__ __launch_bounds__(256) void prep1(
    const int* __restrict__ edst_iu, int* __restrict__ bh_u,
    const int* __restrict__ edst_ui, int* __restrict__ bh_i,
    const float* __restrict__ Wl_iu, const float* __restrict__ Wr_iu,
    const float* __restrict__ Wl_ui, const float* __restrict__ Wr_ui,
    const float* __restrict__ W_user, const float* __restrict__ W_item,
    unsigned short* __restrict__ Wp_user, unsigned short* __restrict__ Wp_item,
    const float* __restrict__ bl_iu, const float* __restrict__ b_user,
    const float* __restrict__ bl_ui, const float* __restrict__ b_item,
    float* __restrict__ bias_user, float* __restrict__ bias_item,
    const float* __restrict__ x_user, const float* __restrict__ x_item,
    unsigned short* __restrict__ xb_user, unsigned short* __restrict__ xb_item)
{
  __shared__ int h[NBIN];
  int b = blockIdx.x, t = threadIdx.x;
  if (b < PB_W0) {
    // ---- MSD histogram (LDS atomics only) ----
    bool uside = b < PB_HIST;
    const int* ed = uside ? edst_iu : edst_ui;
    int* bh       = uside ? bh_u : bh_i;
    int lb        = uside ? b : b - PB_HIST;
    h[t] = 0; h[t + 256] = 0;
    __syncthreads();
    int idx = lb * 1024 + t * 4;
    if (idx < EE) {                       // EE%4==0 -> whole int4 valid
      int4 d = *(const int4*)(ed + idx);
      atomicAdd(&h[d.x >> 9], 1);
      atomicAdd(&h[d.y >> 9], 1);
      atomicAdd(&h[d.z >> 9], 1);
      atomicAdd(&h[d.w >> 9], 1);
    }
    __syncthreads();
    bh[t * EB2 + lb] = h[t];
    bh[(t + 256) * EB2 + lb] = h[t + 256];
  } else if (b < PB_B0) {
    // ---- fused weights ----
    int flat = (b - PB_W0) * 256 + t;     // 0..65535
    int hh = flat & 127, d = (flat >> 7) & 127, m = flat >> 14;
    const float* A; const float* W; unsigned short* dst; int koff;
    switch (m) {
      case 0:  A = Wl_iu; W = W_user; dst = Wp_user; koff = 0;   break;
      case 1:  A = Wr_iu; W = W_user; dst = Wp_user; koff = 128; break;
      case 2:  A = Wl_ui; W = W_item; dst = Wp_item; koff = 0;   break;
      default: A = Wr_ui; W = W_item; dst = Wp_item; koff = 128; break;
    }
    float acc = 0.f;
    for (int k = 0; k < 128; ++k) acc += A[d * 128 + k] * W[k * 128 + hh];
    int kg = koff + d;
    int ks = kg >> 5, quad = (kg >> 3) & 3, j = kg & 7;
    int nt = hh >> 4, nlo = hh & 15;
    dst[((nt * 8 + ks) * 64 + quad * 16 + nlo) * 8 + j] = f2bf(acc);
  } else if (b == PB_B0) {
    // ---- fused bias ----
    int pair = t >> 7, hh = t & 127;
    const float* bl = pair ? bl_ui : bl_iu;
    const float* b2 = pair ? b_item : b_user;
    const float* W  = pair ? W_item : W_user;
    float* o        = pair ? bias_item : bias_user;
    float acc = b2[hh];
    for (int k = 0; k < 128; ++k) acc += bl[k] * W[k * 128 + hh];
    o[hh] = acc;
  } else {
    // ---- fp32 -> bf16 conversion (exact block coverage) ----
    const float* src; unsigned short* dst; long base;
    if (b < PB_CI0) { src = x_user; dst = xb_user; base = (long)(b - PB_CU0) * 2048 + t * 8; }
    else            { src = x_item; dst = xb_item; base = (long)(b - PB_CI0) * 2048 + t * 8; }
    const float4* p4 = (const float4*)(src + base);
    float4 lo = p4[0], hi = p4[1];
    uint4 p;
    p.x = (unsigned)f2bf(lo.x) | ((unsigned)f2bf(lo.y) << 16);
    p.y = (unsigned)f2bf(lo.z) | ((unsigned)f2bf(lo.w) << 16);
    p.z = (unsigned)f2bf(hi.x) | ((unsigned)f2bf(hi.y) << 16);
    p.w = (unsigned)f2bf(hi.z) | ((unsigned)f2bf(hi.w) << 16);
    *(uint4*)(dst + base) = p;
  }
}

// ---------------------------------------------------------------------------
// prep2: bin totals + exclusive bin bases (bb[0..512]) + in-place conversion of
// bh[bin][block] counts into per-(bin,block) scatter start offsets.
// One workgroup per side (512 threads; thread = bin).
// ---------------------------------------------------------------------------
__global__ __launch_bounds__(512) void prep2(
    int* __restrict__ bh_u, int* __restrict__ bb_u,
    int* __restrict__ bh_i, int* __restrict__ bb_i)
{
  __shared__ int s[512];
  int side = blockIdx.x, t = threadIdx.x;
  int* bh = side ? bh_i : bh_u;
  int* bb = side ? bb_i : bb_u;
  int rowbase = t * EB2;
  int tot = 0;
  for (int b = 0; b < EB2; ++b) tot += bh[rowbase + b];
  s[t] = tot; __syncthreads();
  for (int off = 1; off < 512; off <<= 1) {      // inclusive Hillis-Steele
    int v = t >= off ? s[t - off] : 0;
    __syncthreads();
    s[t] += v;
    __syncthreads();
  }
  int base = t ? s[t - 1] : 0;                   // exclusive
  bb[t] = base;
  if (t == 511) bb[512] = s[511];                // = EE
  int run = base;
  for (int b = 0; b < EB2; ++b) {
    int v = bh[rowbase + b];
    bh[rowbase + b] = run;
    run += v;
  }
}

// ---------------------------------------------------------------------------
// prep3: scatter (src,dst) pairs into dst-bucket order. Within-bin rank via
// LDS atomics (order within a node is arbitrary -> fine, mean is commutative).
// ---------------------------------------------------------------------------
__global__ __launch_bounds__(256) void prep3(
    const int* __restrict__ esrc_iu, const int* __restrict__ edst_iu,
    const int* __restrict__ bh_u, int2* __restrict__ tmp_u,
    const int* __restrict__ esrc_ui, const int* __restrict__ edst_ui,
    const int* __restrict__ bh_i, int2* __restrict__ tmp_i)
{
  __shared__ int ofl[NBIN];
  __shared__ int rk[NBIN];
  int b = blockIdx.x, t = threadIdx.x;
  bool uside = blockIdx.y == 0;
  const int* es = uside ? esrc_iu : esrc_ui;
  const int* ed = uside ? edst_iu : edst_ui;
  const int* bh = uside ? bh_u : bh_i;
  int2* tmp     = uside ? tmp_u : tmp_i;
  ofl[t] = bh[t * EB2 + b];
  ofl[t + 256] = bh[(t + 256) * EB2 + b];
  rk[t] = 0; rk[t + 256] = 0;
  __syncthreads();
  int idx = b * 1024 + t * 4;
  if (idx < EE) {
    int4 s4 = *(const int4*)(es + idx);
    int4 d4 = *(const int4*)(ed + idx);
    int bn, r;
    bn = d4.x >> 9; r = atomicAdd(&rk[bn], 1); tmp[ofl[bn] + r] = make_int2(s4.x, d4.x);
    bn = d4.y >> 9; r = atomicAdd(&rk[bn], 1); tmp[ofl[bn] + r] = make_int2(s4.y, d4.y);
    bn = d4.z >> 9; r = atomicAdd(&rk[bn], 1); tmp[ofl[bn] + r] = make_int2(s4.z, d4.z);
    bn = d4.w >> 9; r = atomicAdd(&rk[bn], 1); tmp[ofl[bn] + r] = make_int2(s4.w, d4.w);
  }
}

// ---------------------------------------------------------------------------
// prep4: per 512-node bucket, build CSR: LDS per-node count -> LDS scan ->
// rowp + ranked srcs. All atomics in LDS.
// ---------------------------------------------------------------------------
__global__ __launch_bounds__(256) void prep4(
    const int2* __restrict__ tmp_u, const int* __restrict__ bb_u,
    int* __restrict__ row_u, int* __restrict__ srcs_u,
    const int2* __restrict__ tmp_i, const int* __restrict__ bb_i,
    int* __restrict__ row_i, int* __restrict__ srcs_i)
{
  int bin = blockIdx.x, t = threadIdx.x;
  bool uside = blockIdx.y == 0;
  int nbins = uside ? BINS_U : BINS_I;
  if (bin >= nbins) return;
  int N = uside ? NUu : NIi;
  const int2* tmp = uside ? tmp_u : tmp_i;
  const int* bb   = uside ? bb_u : bb_i;
  int* rowp       = uside ? row_u : row_i;
  int* srcs       = uside ? srcs_u : srcs_i;
  int ebase = bb[bin], eend = bb[bin + 1];
  int node0 = bin << 9;

  __shared__ int cnt[512];
  __shared__ int off[512];
  __shared__ int s1[256];
  cnt[t] = 0; cnt[t + 256] = 0;
  __syncthreads();
  for (int e = ebase + t; e < eend; e += 256)
    atomicAdd(&cnt[tmp[e].y - node0], 1);
  __syncthreads();
  // exclusive scan of cnt[0..511]
  int a = cnt[2 * t], b2 = cnt[2 * t + 1];
  s1[t] = a + b2; __syncthreads();
  for (int o = 1; o < 256; o <<= 1) {
    int v = t >= o ? s1[t - o] : 0;
    __syncthreads();
    s1[t] += v;
    __syncthreads();
  }
  int base = t ? s1[t - 1] : 0;
  off[2 * t] = base;
  off[2 * t + 1] = base + a;
  __syncthreads();
  // rowp (nodes beyond N skipped; gemm substitutes EE past N)
  int nloc = N - node0; if (nloc > 512) nloc = 512;
  if (t < nloc)       rowp[node0 + t]       = ebase + off[t];
  if (t + 256 < nloc) rowp[node0 + t + 256] = ebase + off[t + 256];
  // rank pass (reuse cnt as rank counters)
  cnt[t] = 0; cnt[t + 256] = 0;
  __syncthreads();
  for (int e = ebase + t; e < eend; e += 256) {
    int2 p = tmp[e];
    int l = p.y - node0;
    int r = atomicAdd(&cnt[l], 1);
    srcs[ebase + off[l] + r] = p.x;
  }
}

// ---------------------------------------------------------------------------
// K3 (R6-proven, UNCHANGED): fused node kernel.
//  BF=true: bf16 gather rows (256B), 77MB working set L3-resident.
//  Output: NT scattered stores. SCAP 768, 8 blocks/CU.
// mfma_f32_16x16x32_bf16 C/D: col=lane&15, row=(lane>>4)*4+reg   (m89/m91)
// ---------------------------------------------------------------------------
template<bool BF>
__global__ __launch_bounds__(256, 8) void fused_gemm(
    const void* __restrict__ xu_own, const void* __restrict__ xu_src,
    const int* __restrict__ rowp_u, const int* __restrict__ srcs_u,
    const unsigned short* __restrict__ Wp_u, const float* __restrict__ bias_u,
    const void* __restrict__ xi_own, const void* __restrict__ xi_src,
    const int* __restrict__ rowp_i, const int* __restrict__ srcs_i,
    const unsigned short* __restrict__ Wp_i, const float* __restrict__ bias_i,
    float* __restrict__ out)
{
  __shared__ __align__(16) uint4 ldsA4[1024];    // 16 KB packed A (half of K)
  __shared__ int ldsS[SCAP];                     // 3 KB src-index window
  __shared__ int rb[65];
  int t = threadIdx.x;
  int b = blockIdx.x;

  const void* xown; const void* xsrc; const int* rowp; const int* srcs;
  const unsigned short* Wp; const float* bias; float* outbase; int nvalid; int node0;
  if (b < NB_USER) {
    xown = xu_own; xsrc = xu_src; rowp = rowp_u; srcs = srcs_u;
    Wp = Wp_u; bias = bias_u; outbase = out; nvalid = NUu; node0 = b * 64;
  } else {
    xown = xi_own; xsrc = xi_src; rowp = rowp_i; srcs = srcs_i;
    Wp = Wp_i; bias = bias_i; outbase = out + (size_t)NUu * 128;
    nvalid = NIi; node0 = (b - NB_USER) * 64;
  }

  // ---- phase 0: row pointers + src-index window ----
  if (t < 65) {
    int node = node0 + t;
    rb[t] = node < nvalid ? rowp[node] : EE;
  }
  __syncthreads();
  int rs0 = rb[0];
  int W = rb[64] - rs0;
  for (int idx = t; idx < W && idx < SCAP; idx += 256)
    ldsS[idx] = srcs[rs0 + idx];

  // ---- phase 1: own-half (K=128..255) pack into swizzled A slots ----
  #pragma unroll
  for (int i = 0; i < 4; ++i) {
    int oid = t + i * 256;
    int m = oid >> 4;                            // node within block
    int oct = oid & 15;                          // 8-elem k-slice
    int node = node0 + m;
    uint4 p; p.x = 0u; p.y = 0u; p.z = 0u; p.w = 0u;
    if (node < nvalid) {
      if constexpr (BF) {
        p = *(const uint4*)((const unsigned short*)xown + (size_t)node * 128 + oct * 8);
      } else {
        const float4* p4 = (const float4*)((const float*)xown + (size_t)node * 128 + oct * 8);
        float4 lo = p4[0], hi = p4[1];
        p.x = (unsigned)f2bf(lo.x) | ((unsigned)f2bf(lo.y) << 16);
        p.y = (unsigned)f2bf(lo.z) | ((unsigned)f2bf(lo.w) << 16);
        p.z = (unsigned)f2bf(hi.x) | ((unsigned)f2bf(hi.y) << 16);
        p.w = (unsigned)f2bf(hi.z) | ((unsigned)f2bf(hi.w) << 16);
      }
    }
    int ks = oct >> 2, quad = oct & 3;
    int mt = m >> 4, mlo = m & 15;
    ldsA4[(mt * 4 + ks) * 64 + quad * 16 + (mlo ^ (oct & 7))] = p;
  }
  __syncthreads();

  // ---- phase 2: MFMA own half (k_global 128..255) ----
  int wave = t >> 6, lane = t & 63;
  int quadr = lane >> 4, mlor = lane & 15;
  floatx4 acc[8];
  #pragma unroll
  for (int i = 0; i < 8; ++i) acc[i] = (floatx4){0.f, 0.f, 0.f, 0.f};
  const short8* A = (const short8*)ldsA4;
  const short8* B = (const short8*)Wp;
  #pragma unroll
  for (int kk = 0; kk < 4; ++kk) {
    short8 af = A[(wave * 4 + kk) * 64 + quadr * 16 + (mlor ^ ((kk * 4 + quadr) & 7))];
    #pragma unroll
    for (int nt = 0; nt < 8; ++nt) {
      short8 bf = B[(nt * 8 + 4 + kk) * 64 + lane];
      acc[nt] = __builtin_amdgcn_mfma_f32_16x16x32_bf16(af, bf, acc[nt], 0, 0, 0);
    }
  }
  __syncthreads();                               // ldsA consumed, safe to refill

  // ---- phase 3: gather+mean, parity-split (all 32 lanes per node) ----
  #pragma unroll
  for (int i = 0; i < 8; ++i) {
    int oid = t + i * 256;
    int m = oid >> 5;
    int oct = oid & 31;
    int slice = oct & 15;
    int par = oct >> 4;
    int node = node0 + m;
    float a0=0,a1=0,a2=0,a3=0,a4=0,a5=0,a6=0,a7=0;
    int deg = 0;
    if (node < nvalid) {
      int erel = rb[m] - rs0;
      deg = rb[m + 1] - rb[m];
      int k0 = slice * 8;
      int e = par;
      if constexpr (BF) {
        const unsigned short* xs = (const unsigned short*)xsrc;
        for (; e + 2 < deg; e += 4) {
          int q0 = erel + e, q1 = q0 + 2;
          int s0 = (q0 < SCAP) ? ldsS[q0] : srcs[rs0 + q0];
          int s1 = (q1 < SCAP) ? ldsS[q1] : srcs[rs0 + q1];
          uint4 v0 = *(const uint4*)(xs + (size_t)s0 * 128 + k0);
          uint4 v1 = *(const uint4*)(xs + (size_t)s1 * 128 + k0);
          a0 += bflo(v0.x) + bflo(v1.x); a1 += bfhi(v0.x) + bfhi(v1.x);
          a2 += bflo(v0.y) + bflo(v1.y); a3 += bfhi(v0.y) + bfhi(v1.y);
          a4 += bflo(v0.z) + bflo(v1.z); a5 += bfhi(v0.z) + bfhi(v1.z);
          a6 += bflo(v0.w) + bflo(v1.w); a7 += bfhi(v0.w) + bfhi(v1.w);
        }
        if (e < deg) {
          int q = erel + e;
          int s = (q < SCAP) ? ldsS[q] : srcs[rs0 + q];
          uint4 v0 = *(const uint4*)(xs + (size_t)s * 128 + k0);
          a0 += bflo(v0.x); a1 += bfhi(v0.x);
          a2 += bflo(v0.y); a3 += bfhi(v0.y);
          a4 += bflo(v0.z); a5 += bfhi(v0.z);
          a6 += bflo(v0.w); a7 += bfhi(v0.w);
        }
      } else {
        const float* xs = (const float*)xsrc;
        for (; e + 2 < deg; e += 4) {
          int q0 = erel + e, q1 = q0 + 2;
          int s0 = (q0 < SCAP) ? ldsS[q0] : srcs[rs0 + q0];
          int s1 = (q1 < SCAP) ? ldsS[q1] : srcs[rs0 + q1];
          const float4* r0 = (const float4*)(xs + (size_t)s0 * 128 + k0);
          const float4* r1 = (const float4*)(xs + (size_t)s1 * 128 + k0);
          float4 l0 = r0[0], h0 = r0[1];
          float4 l1 = r1[0], h1 = r1[1];
          a0 += l0.x + l1.x; a1 += l0.y + l1.y;
          a2 += l0.z + l1.z; a3 += l0.w + l1.w;
          a4 += h0.x + h1.x; a5 += h0.y + h1.y;
          a6 += h0.z + h1.z; a7 += h0.w + h1.w;
        }
        if (e < deg) {
          int q = erel + e;
          int s = (q < SCAP) ? ldsS[q] : srcs[rs0 + q];
          const float4* r = (const float4*)(xs + (size_t)s * 128 + k0);
          float4 l = r[0], h = r[1];
          a0 += l.x; a1 += l.y; a2 += l.z; a3 += l.w;
          a4 += h.x; a5 += h.y; a6 += h.z; a7 += h.w;
        }
      }
    }
    a0 += __shfl_xor(a0, 16); a1 += __shfl_xor(a1, 16);
    a2 += __shfl_xor(a2, 16); a3 += __shfl_xor(a3, 16);
    a4 += __shfl_xor(a4, 16); a5 += __shfl_xor(a5, 16);
    a6 += __shfl_xor(a6, 16); a7 += __shfl_xor(a7, 16);
    if (par == 0) {
      float sc = deg > 0 ? 1.0f / (float)deg : 0.f;
      uint4 p;
      p.x = (unsigned)f2bf(a0 * sc) | ((unsigned)f2bf(a1 * sc) << 16);
      p.y = (unsigned)f2bf(a2 * sc) | ((unsigned)f2bf(a3 * sc) << 16);
      p.z = (unsigned)f2bf(a4 * sc) | ((unsigned)f2bf(a5 * sc) << 16);
      p.w = (unsigned)f2bf(a6 * sc) | ((unsigned)f2bf(a7 * sc) << 16);
      int ks = slice >> 2, quad = slice & 3;
      int mt = m >> 4, mlo = m & 15;
      ldsA4[(mt * 4 + ks) * 64 + quad * 16 + (mlo ^ (slice & 7))] = p;
    }
  }
  __syncthreads();

  // ---- phase 4: MFMA agg half (k_global 0..127) ----
  #pragma unroll
  for (int kk = 0; kk < 4; ++kk) {
    short8 af = A[(wave * 4 + kk) * 64 + quadr * 16 + (mlor ^ ((kk * 4 + quadr) & 7))];
    #pragma unroll
    for (int nt = 0; nt < 8; ++nt) {
      short8 bf = B[(nt * 8 + kk) * 64 + lane];
      acc[nt] = __builtin_amdgcn_mfma_f32_16x16x32_bf16(af, bf, acc[nt], 0, 0, 0);
    }
  }

  // ---- epilogue: bias + relu, NT scattered stores (out never re-read) ----
  int col = lane & 15, qrow = (lane >> 4) * 4;
  #pragma unroll
  for (int nt = 0; nt < 8; ++nt) {
    int n = nt * 16 + col;
    float bv = bias[n];
    #pragma unroll
    for (int r2 = 0; r2 < 4; ++r2) {
      int node = node0 + wave * 16 + qrow + r2;
      if (node < nvalid) {
        float v = acc[nt][r2] + bv;
        v = v > 0.f ? v : 0.f;
        __builtin_nontemporal_store(v, &outbase[(size_t)node * 128 + n]);
      }
    }
  }
}

// ---------------------------------------------------------------------------
// Workspace layout (bytes) — nothing needs zeroing (all fully rewritten):
//   bh_user @0 1200128 | bh_item @1200128 1200128
//   bb_user @2400256 2052 | bb_item @2402308 2052 | (pad)
//   tmp_user @2404864 4800000 | tmp_item @7204864 4800000
//   row_user @12004864 800000 | row_item @12804864 400000
//   srcs_user @13204864 2400000 | srcs_item @15604864 2400000
//   Wp_user @18004864 65536 | Wp_item @18070400 65536
//   bias_user @18135936 512 | bias_item @18136448 512
//   xb_user @18136960 51200000 | xb_item @69336960 25600000 | end 94936960
// ---------------------------------------------------------------------------
extern "C" void kernel_launch(void* const* d_in, const int* in_sizes, int n_in,
                              void* d_out, int out_size, void* d_ws, size_t ws_size,
                              hipStream_t stream)
{
  const float* x_user = (const float*)d_in[0];
  const float* x_item = (const float*)d_in[1];
  const int* esrc_ui  = (const int*)d_in[2];
  const int* edst_ui  = (const int*)d_in[3];
  const int* esrc_iu  = (const int*)d_in[4];
  const int* edst_iu  = (const int*)d_in[5];
  const float* Wl_ui  = (const float*)d_in[6];
  const float* bl_ui  = (const float*)d_in[7];
  const float* Wr_ui  = (const float*)d_in[8];
  const float* Wl_iu  = (const float*)d_in[9];
  const float* bl_iu  = (const float*)d_in[10];
  const float* Wr_iu  = (const float*)d_in[11];
  const float* W_user = (const float*)d_in[12];
  const float* b_user = (const float*)d_in[13];
  const float* W_item = (const float*)d_in[14];
  const float* b_item = (const float*)d_in[15];
  float* out = (float*)d_out;

  char* ws = (char*)d_ws;
  int* bh_u      = (int*)(ws + 0);
  int* bh_i      = (int*)(ws + 1200128);
  int* bb_u      = (int*)(ws + 2400256);
  int* bb_i      = (int*)(ws + 2402308);
  int2* tmp_u    = (int2*)(ws + 2404864);
  int2* tmp_i    = (int2*)(ws + 7204864);
  int* row_user  = (int*)(ws + 12004864UL);
  int* row_item  = (int*)(ws + 12804864UL);
  int* srcs_user = (int*)(ws + 13204864UL);
  int* srcs_item = (int*)(ws + 15604864UL);
  unsigned short* Wp_user = (unsigned short*)(ws + 18004864UL);
  unsigned short* Wp_item = (unsigned short*)(ws + 18070400UL);
  float* bias_user = (float*)(ws + 18135936UL);
  float* bias_item = (float*)(ws + 18136448UL);
  unsigned short* xb_user = (unsigned short*)(ws + 18136960UL);
  unsigned short* xb_item = (unsigned short*)(ws + 69336960UL);

  const bool bf = ws_size >= 94936960UL;

  prep1<<<bf ? PB_END : PB_CU0, 256, 0, stream>>>(
      edst_iu, bh_u, edst_ui, bh_i,
      Wl_iu, Wr_iu, Wl_ui, Wr_ui, W_user, W_item, Wp_user, Wp_item,
      bl_iu, b_user, bl_ui, b_item, bias_user, bias_item,
      x_user, x_item, xb_user, xb_item);

  prep2<<<2, 512, 0, stream>>>(bh_u, bb_u, bh_i, bb_i);

  prep3<<<dim3(EB2, 2), 256, 0, stream>>>(
      esrc_iu, edst_iu, bh_u, tmp_u,
      esrc_ui, edst_ui, bh_i, tmp_i);

  prep4<<<dim3(BINS_U, 2), 256, 0, stream>>>(
      tmp_u, bb_u, row_user, srcs_user,
      tmp_i, bb_i, row_item, srcs_item);

  if (bf) {
    fused_gemm<true><<<NB_USER + NB_ITEM, 256, 0, stream>>>(
        xb_user, xb_item, row_user, srcs_user, Wp_user, bias_user,
        xb_item, xb_user, row_item, srcs_item, Wp_item, bias_item, out);
  } else {
    fused_gemm<false><<<NB_USER + NB_ITEM, 256, 0, stream>>>(
        x_user, x_item, row_user, srcs_user, Wp_user, bias_user,
        x_item, x_user, row_item, srcs_item, Wp_item, bias_item, out);
  }
}

// Round 9
// 538.507 us; speedup vs baseline: 1.2705x; 1.2705x over previous
//
#include <hip/hip_runtime.h>

// Problem constants (from reference)
#define NUu 200000
#define NIi 100000
#define EE  600000
// D = H = 128

#define SCAP 768      // LDS src-index window (block windows avg 192/384; global fallback covers)
#define NB_USER 3125  // (NUu+63)/64
#define NB_ITEM 1563  // (NIi+63)/64
#define HB 586        // ceil(EE/1024) edge blocks
#define NREP 8        // XCD-local counter replicas; edge-block b uses replica b&7

// conv_weights grid sections: [0,256) weights | {256} bias | [257,12757) conv user | [12757,19007) conv item
#define CW_BIAS 256
#define CW_CVU  257
#define CW_CVI  12757
#define CW_END  19007

typedef short short8 __attribute__((ext_vector_type(8)));
typedef float floatx4 __attribute__((ext_vector_type(4)));

// float -> bf16 bits, round-to-nearest-even
__device__ __forceinline__ unsigned short f2bf(float f) {
  union { float f; unsigned int u; } v; v.f = f;
  unsigned int r = v.u + 0x7FFFu + ((v.u >> 16) & 1u);
  return (unsigned short)(r >> 16);
}
// bf16 pair (packed in u32) -> f32
__device__ __forceinline__ float bflo(unsigned int u) { return __uint_as_float(u << 16); }
__device__ __forceinline__ float bfhi(unsigned int u) { return __uint_as_float(u & 0xFFFF0000u); }

// ---------------------------------------------------------------------------
// conv_weights (R6-proven, unchanged): streaming preprocessing (no atomics)
// ---------------------------------------------------------------------------
__global__ __launch_bounds__(256) void conv_weights(
    const float* __restrict__ Wl_iu, const float* __restrict__ Wr_iu,
    const float* __restrict__ Wl_ui, const float* __restrict__ Wr_ui,
    const float* __restrict__ W_user, const float* __restrict__ W_item,
    unsigned short* __restrict__ Wp_user, unsigned short* __restrict__ Wp_item,
    const float* __restrict__ bl_iu, const float* __restrict__ b_user,
    const float* __restrict__ bl_ui, const float* __restrict__ b_item,
    float* __restrict__ bias_user, float* __restrict__ bias_item,
    const float* __restrict__ x_user, const float* __restrict__ x_item,
    unsigned short* __restrict__ xb_user, unsigned short* __restrict__ xb_item)
{
  int b = blockIdx.x, t = threadIdx.x;
  if (b < CW_BIAS) {
    // ---- fused weights: W1=Wl@W2, W2=Wr@W2 -> bf16 MFMA B-frag layout ----
    int flat = b * 256 + t;               // 0..65535
    int h = flat & 127, d = (flat >> 7) & 127, m = flat >> 14;
    const float* A; const float* W; unsigned short* dst; int koff;
    switch (m) {
      case 0:  A = Wl_iu; W = W_user; dst = Wp_user; koff = 0;   break;
      case 1:  A = Wr_iu; W = W_user; dst = Wp_user; koff = 128; break;
      case 2:  A = Wl_ui; W = W_item; dst = Wp_item; koff = 0;   break;
      default: A = Wr_ui; W = W_item; dst = Wp_item; koff = 128; break;
    }
    float acc = 0.f;
    for (int k = 0; k < 128; ++k) acc += A[d * 128 + k] * W[k * 128 + h];
    int kg = koff + d;
    int ks = kg >> 5, quad = (kg >> 3) & 3, j = kg & 7;
    int nt = h >> 4, nlo = h & 15;
    dst[((nt * 8 + ks) * 64 + quad * 16 + nlo) * 8 + j] = f2bf(acc);
  } else if (b == CW_BIAS) {
    // ---- fused bias ----
    int pair = t >> 7, h = t & 127;
    const float* bl = pair ? bl_ui : bl_iu;
    const float* b2 = pair ? b_item : b_user;
    const float* W  = pair ? W_item : W_user;
    float* o        = pair ? bias_item : bias_user;
    float acc = b2[h];
    for (int k = 0; k < 128; ++k) acc += bl[k] * W[k * 128 + h];
    o[h] = acc;
  } else {
    // ---- fp32 -> bf16 conversion (exact block coverage) ----
    const float* src; unsigned short* dst; long base;
    if (b < CW_CVI) { src = x_user; dst = xb_user; base = (long)(b - CW_CVU) * 2048 + t * 8; }
    else            { src = x_item; dst = xb_item; base = (long)(b - CW_CVI) * 2048 + t * 8; }
    const float4* p4 = (const float4*)(src + base);
    float4 lo = p4[0], hi = p4[1];
    uint4 p;
    p.x = (unsigned)f2bf(lo.x) | ((unsigned)f2bf(lo.y) << 16);
    p.y = (unsigned)f2bf(lo.z) | ((unsigned)f2bf(lo.w) << 16);
    p.z = (unsigned)f2bf(hi.x) | ((unsigned)f2bf(hi.y) << 16);
    p.w = (unsigned)f2bf(hi.z) | ((unsigned)f2bf(hi.w) << 16);
    *(uint4*)(dst + base) = p;
  }
}

// ---------------------------------------------------------------------------
// hist_slots: histogram + slot memoization into XCD-LOCAL replica b&7.
// Dispatch round-robins blocks over XCDs -> replica r is touched by ~one XCD
// -> atomic lines stay in that XCD's L2 (no cross-XCD ping-pong). Correctness
// does not depend on the mapping. slot is replica-local rank.
// ---------------------------------------------------------------------------
__global__ __launch_bounds__(256) void hist_slots(
    const int* __restrict__ edst_iu, int* __restrict__ cr_u, int* __restrict__ slots_u,
    const int* __restrict__ edst_ui, int* __restrict__ cr_i, int* __restrict__ slots_i)
{
  int b = blockIdx.x, t = threadIdx.x;
  const int* ed = blockIdx.y ? edst_ui : edst_iu;
  int* cr       = blockIdx.y ? cr_i : cr_u;
  int* slots    = blockIdx.y ? slots_i : slots_u;
  int N         = blockIdx.y ? NIi : NUu;
  int* cnt = cr + (b & (NREP - 1)) * N;
  int idx = b * 1024 + t * 4;
  if (idx < EE) {                          // EE%4==0 -> whole int4 valid
    int4 d = *(const int4*)(ed + idx);
    int4 p;
    p.x = atomicAdd(&cnt[d.x], 1);
    p.y = atomicAdd(&cnt[d.y], 1);
    p.z = atomicAdd(&cnt[d.z], 1);
    p.w = atomicAdd(&cnt[d.w], 1);
    *(int4*)(slots + idx) = p;             // sequential streaming write
  }
}

// ---------------------------------------------------------------------------
// scan1: per-1024-node chunk sums of TOTAL degree (sum over 8 replicas).
// ---------------------------------------------------------------------------
__global__ __launch_bounds__(256) void scan1(
    const int* __restrict__ cr_u, int* __restrict__ blk_u,
    const int* __restrict__ cr_i, int* __restrict__ blk_i)
{
  __shared__ int s[256];
  int b = blockIdx.x, t = threadIdx.x;
  const int* cr; int* blksum; int N;
  if (blockIdx.y == 0) { cr = cr_u; blksum = blk_u; N = NUu; }
  else { if (b >= 98) return; cr = cr_i; blksum = blk_i; N = NIi; }
  int base = b * 1024 + t * 4;
  int v = 0;
  #pragma unroll
  for (int r = 0; r < NREP; ++r) {
    const int* c = cr + r * N;
    #pragma unroll
    for (int j = 0; j < 4; ++j) { int i = base + j; if (i < N) v += c[i]; }
  }
  s[t] = v; __syncthreads();
  for (int off = 128; off > 0; off >>= 1) {
    if (t < off) s[t] += s[t + off];
    __syncthreads();
  }
  if (t == 0) blksum[b] = s[0];
}

// ---------------------------------------------------------------------------
// scan3: chunk offset from blksums (local re-scan, absorbs scan2) -> rowp;
// then converts cnt[r][n] IN-PLACE into base offsets:
//   base[r][n] = rowp[n] + sum_{r'<r} cnt[r'][n]
// so fill is non-atomic: pos = base[rep][dst] + slot.
// ---------------------------------------------------------------------------
__global__ __launch_bounds__(256) void scan3(
    int* __restrict__ cr_u, const int* __restrict__ blks_u, int* __restrict__ row_u,
    int* __restrict__ cr_i, const int* __restrict__ blks_i, int* __restrict__ row_i)
{
  __shared__ int s[256];
  int b = blockIdx.x, t = threadIdx.x;
  int* cr; const int* blksum; int* rowp; int N; int nblk;
  if (blockIdx.y == 0) { cr = cr_u; blksum = blks_u; rowp = row_u; N = NUu; nblk = 196; }
  else { if (b >= 98) return; cr = cr_i; blksum = blks_i; rowp = row_i; N = NIi; nblk = 98; }

  int v2 = t < nblk ? blksum[t] : 0;
  s[t] = v2; __syncthreads();
  for (int off = 1; off < 256; off <<= 1) {
    int tmp = t >= off ? s[t - off] : 0;
    __syncthreads();
    s[t] += tmp;
    __syncthreads();
  }
  int blkoffb = (b == 0) ? 0 : s[b - 1];
  __syncthreads();

  int base = b * 1024 + t * 4;
  int tot[4]; int sum = 0;
  #pragma unroll
  for (int j = 0; j < 4; ++j) {
    int i = base + j; int v = 0;
    if (i < N) {
      #pragma unroll
      for (int r = 0; r < NREP; ++r) v += cr[r * N + i];
    }
    tot[j] = v; sum += v;
  }
  s[t] = sum; __syncthreads();
  for (int off = 1; off < 256; off <<= 1) {
    int tmp = t >= off ? s[t - off] : 0;
    __syncthreads();
    s[t] += tmp;
    __syncthreads();
  }
  int ex = s[t] - sum + blkoffb;
  #pragma unroll
  for (int j = 0; j < 4; ++j) {
    int i = base + j;
    if (i < N) {
      rowp[i] = ex;
      int run = ex;
      #pragma unroll
      for (int r = 0; r < NREP; ++r) {
        int c = cr[r * N + i];
        cr[r * N + i] = run;               // cnt -> base (in place)
        run += c;
      }
      ex += tot[j];
    }
  }
}

// ---------------------------------------------------------------------------
// fill_ns: NON-ATOMIC fill. rep = block&7 (same mapping as hist_slots).
// pos = base[rep][dst] + replica-local slot.
// ---------------------------------------------------------------------------
__global__ __launch_bounds__(256) void fill_ns(
    const int* __restrict__ esrc_iu, const int* __restrict__ edst_iu,
    const int* __restrict__ slots_u, const int* __restrict__ cr_u, int* __restrict__ srcs_u,
    const int* __restrict__ esrc_ui, const int* __restrict__ edst_ui,
    const int* __restrict__ slots_i, const int* __restrict__ cr_i, int* __restrict__ srcs_i)
{
  int b = blockIdx.x, t = threadIdx.x;
  const int* es; const int* ed; const int* sl; const int* cr; int* srcs; int N;
  if (blockIdx.y == 0) { es = esrc_iu; ed = edst_iu; sl = slots_u; cr = cr_u; srcs = srcs_u; N = NUu; }
  else                 { es = esrc_ui; ed = edst_ui; sl = slots_i; cr = cr_i; srcs = srcs_i; N = NIi; }
  const int* base = cr + (b & (NREP - 1)) * N;
  int idx = b * 1024 + t * 4;
  if (idx < EE) {
    int4 s = *(const int4*)(es + idx);
    int4 d = *(const int4*)(ed + idx);
    int4 p = *(const int4*)(sl + idx);
    srcs[base[d.x] + p.x] = s.x;
    srcs[base[d.y] + p.y] = s.y;
    srcs[base[d.z] + p.z] = s.z;
    srcs[base[d.w] + p.w] = s.w;
  }
}

// ---------------------------------------------------------------------------
// K3 (R6-proven, UNCHANGED): fused node kernel. 177us control.
// mfma_f32_16x16x32_bf16 C/D: col=lane&15, row=(lane>>4)*4+reg   (m89/m91)
// ---------------------------------------------------------------------------
template<bool BF>
__global__ __launch_bounds__(256, 8) void fused_gemm(
    const void* __restrict__ xu_own, const void* __restrict__ xu_src,
    const int* __restrict__ rowp_u, const int* __restrict__ srcs_u,
    const unsigned short* __restrict__ Wp_u, const float* __restrict__ bias_u,
    const void* __restrict__ xi_own, const void* __restrict__ xi_src,
    const int* __restrict__ rowp_i, const int* __restrict__ srcs_i,
    const unsigned short* __restrict__ Wp_i, const float* __restrict__ bias_i,
    float* __restrict__ out)
{
  __shared__ __align__(16) uint4 ldsA4[1024];    // 16 KB packed A (half of K)
  __shared__ int ldsS[SCAP];                     // 3 KB src-index window
  __shared__ int rb[65];
  int t = threadIdx.x;
  int b = blockIdx.x;

  const void* xown; const void* xsrc; const int* rowp; const int* srcs;
  const unsigned short* Wp; const float* bias; float* outbase; int nvalid; int node0;
  if (b < NB_USER) {
    xown = xu_own; xsrc = xu_src; rowp = rowp_u; srcs = srcs_u;
    Wp = Wp_u; bias = bias_u; outbase = out; nvalid = NUu; node0 = b * 64;
  } else {
    xown = xi_own; xsrc = xi_src; rowp = rowp_i; srcs = srcs_i;
    Wp = Wp_i; bias = bias_i; outbase = out + (size_t)NUu * 128;
    nvalid = NIi; node0 = (b - NB_USER) * 64;
  }

  // ---- phase 0: row pointers + src-index window ----
  if (t < 65) {
    int node = node0 + t;
    rb[t] = node < nvalid ? rowp[node] : EE;
  }
  __syncthreads();
  int rs0 = rb[0];
  int W = rb[64] - rs0;
  for (int idx = t; idx < W && idx < SCAP; idx += 256)
    ldsS[idx] = srcs[rs0 + idx];

  // ---- phase 1: own-half (K=128..255) pack into swizzled A slots ----
  #pragma unroll
  for (int i = 0; i < 4; ++i) {
    int oid = t + i * 256;
    int m = oid >> 4;                            // node within block
    int oct = oid & 15;                          // 8-elem k-slice
    int node = node0 + m;
    uint4 p; p.x = 0u; p.y = 0u; p.z = 0u; p.w = 0u;
    if (node < nvalid) {
      if constexpr (BF) {
        p = *(const uint4*)((const unsigned short*)xown + (size_t)node * 128 + oct * 8);
      } else {
        const float4* p4 = (const float4*)((const float*)xown + (size_t)node * 128 + oct * 8);
        float4 lo = p4[0], hi = p4[1];
        p.x = (unsigned)f2bf(lo.x) | ((unsigned)f2bf(lo.y) << 16);
        p.y = (unsigned)f2bf(lo.z) | ((unsigned)f2bf(lo.w) << 16);
        p.z = (unsigned)f2bf(hi.x) | ((unsigned)f2bf(hi.y) << 16);
        p.w = (unsigned)f2bf(hi.z) | ((unsigned)f2bf(hi.w) << 16);
      }
    }
    int ks = oct >> 2, quad = oct & 3;
    int mt = m >> 4, mlo = m & 15;
    ldsA4[(mt * 4 + ks) * 64 + quad * 16 + (mlo ^ (oct & 7))] = p;
  }
  __syncthreads();

  // ---- phase 2: MFMA own half (k_global 128..255) ----
  int wave = t >> 6, lane = t & 63;
  int quadr = lane >> 4, mlor = lane & 15;
  floatx4 acc[8];
  #pragma unroll
  for (int i = 0; i < 8; ++i) acc[i] = (floatx4){0.f, 0.f, 0.f, 0.f};
  const short8* A = (const short8*)ldsA4;
  const short8* B = (const short8*)Wp;
  #pragma unroll
  for (int kk = 0; kk < 4; ++kk) {
    short8 af = A[(wave * 4 + kk) * 64 + quadr * 16 + (mlor ^ ((kk * 4 + quadr) & 7))];
    #pragma unroll
    for (int nt = 0; nt < 8; ++nt) {
      short8 bf = B[(nt * 8 + 4 + kk) * 64 + lane];
      acc[nt] = __builtin_amdgcn_mfma_f32_16x16x32_bf16(af, bf, acc[nt], 0, 0, 0);
    }
  }
  __syncthreads();                               // ldsA consumed, safe to refill

  // ---- phase 3: gather+mean, parity-split (all 32 lanes per node) ----
  #pragma unroll
  for (int i = 0; i < 8; ++i) {
    int oid = t + i * 256;
    int m = oid >> 5;
    int oct = oid & 31;
    int slice = oct & 15;
    int par = oct >> 4;
    int node = node0 + m;
    float a0=0,a1=0,a2=0,a3=0,a4=0,a5=0,a6=0,a7=0;
    int deg = 0;
    if (node < nvalid) {
      int erel = rb[m] - rs0;
      deg = rb[m + 1] - rb[m];
      int k0 = slice * 8;
      int e = par;
      if constexpr (BF) {
        const unsigned short* xs = (const unsigned short*)xsrc;
        for (; e + 2 < deg; e += 4) {
          int q0 = erel + e, q1 = q0 + 2;
          int s0 = (q0 < SCAP) ? ldsS[q0] : srcs[rs0 + q0];
          int s1 = (q1 < SCAP) ? ldsS[q1] : srcs[rs0 + q1];
          uint4 v0 = *(const uint4*)(xs + (size_t)s0 * 128 + k0);
          uint4 v1 = *(const uint4*)(xs + (size_t)s1 * 128 + k0);
          a0 += bflo(v0.x) + bflo(v1.x); a1 += bfhi(v0.x) + bfhi(v1.x);
          a2 += bflo(v0.y) + bflo(v1.y); a3 += bfhi(v0.y) + bfhi(v1.y);
          a4 += bflo(v0.z) + bflo(v1.z); a5 += bfhi(v0.z) + bfhi(v1.z);
          a6 += bflo(v0.w) + bflo(v1.w); a7 += bfhi(v0.w) + bfhi(v1.w);
        }
        if (e < deg) {
          int q = erel + e;
          int s = (q < SCAP) ? ldsS[q] : srcs[rs0 + q];
          uint4 v0 = *(const uint4*)(xs + (size_t)s * 128 + k0);
          a0 += bflo(v0.x); a1 += bfhi(v0.x);
          a2 += bflo(v0.y); a3 += bfhi(v0.y);
          a4 += bflo(v0.z); a5 += bfhi(v0.z);
          a6 += bflo(v0.w); a7 += bfhi(v0.w);
        }
      } else {
        const float* xs = (const float*)xsrc;
        for (; e + 2 < deg; e += 4) {
          int q0 = erel + e, q1 = q0 + 2;
          int s0 = (q0 < SCAP) ? ldsS[q0] : srcs[rs0 + q0];
          int s1 = (q1 < SCAP) ? ldsS[q1] : srcs[rs0 + q1];
          const float4* r0 = (const float4*)(xs + (size_t)s0 * 128 + k0);
          const float4* r1 = (const float4*)(xs + (size_t)s1 * 128 + k0);
          float4 l0 = r0[0], h0 = r0[1];
          float4 l1 = r1[0], h1 = r1[1];
          a0 += l0.x + l1.x; a1 += l0.y + l1.y;
          a2 += l0.z + l1.z; a3 += l0.w + l1.w;
          a4 += h0.x + h1.x; a5 += h0.y + h1.y;
          a6 += h0.z + h1.z; a7 += h0.w + h1.w;
        }
        if (e < deg) {
          int q = erel + e;
          int s = (q < SCAP) ? ldsS[q] : srcs[rs0 + q];
          const float4* r = (const float4*)(xs + (size_t)s * 128 + k0);
          float4 l = r[0], h = r[1];
          a0 += l.x; a1 += l.y; a2 += l.z; a3 += l.w;
          a4 += h.x; a5 += h.y; a6 += h.z; a7 += h.w;
        }
      }
    }
    a0 += __shfl_xor(a0, 16); a1 += __shfl_xor(a1, 16);
    a2 += __shfl_xor(a2, 16); a3 += __shfl_xor(a3, 16);
    a4 += __shfl_xor(a4, 16); a5 += __shfl_xor(a5, 16);
    a6 += __shfl_xor(a6, 16); a7 += __shfl_xor(a7, 16);
    if (par == 0) {
      float sc = deg > 0 ? 1.0f / (float)deg : 0.f;
      uint4 p;
      p.x = (unsigned)f2bf(a0 * sc) | ((unsigned)f2bf(a1 * sc) << 16);
      p.y = (unsigned)f2bf(a2 * sc) | ((unsigned)f2bf(a3 * sc) << 16);
      p.z = (unsigned)f2bf(a4 * sc) | ((unsigned)f2bf(a5 * sc) << 16);
      p.w = (unsigned)f2bf(a6 * sc) | ((unsigned)f2bf(a7 * sc) << 16);
      int ks = slice >> 2, quad = slice & 3;
      int mt = m >> 4, mlo = m & 15;
      ldsA4[(mt * 4 + ks) * 64 + quad * 16 + (mlo ^ (slice & 7))] = p;
    }
  }
  __syncthreads();

  // ---- phase 4: MFMA agg half (k_global 0..127) ----
  #pragma unroll
  for (int kk = 0; kk < 4; ++kk) {
    short8 af = A[(wave * 4 + kk) * 64 + quadr * 16 + (mlor ^ ((kk * 4 + quadr) & 7))];
    #pragma unroll
    for (int nt = 0; nt < 8; ++nt) {
      short8 bf = B[(nt * 8 + kk) * 64 + lane];
      acc[nt] = __builtin_amdgcn_mfma_f32_16x16x32_bf16(af, bf, acc[nt], 0, 0, 0);
    }
  }

  // ---- epilogue: bias + relu, NT scattered stores (out never re-read) ----
  int col = lane & 15, qrow = (lane >> 4) * 4;
  #pragma unroll
  for (int nt = 0; nt < 8; ++nt) {
    int n = nt * 16 + col;
    float bv = bias[n];
    #pragma unroll
    for (int r2 = 0; r2 < 4; ++r2) {
      int node = node0 + wave * 16 + qrow + r2;
      if (node < nvalid) {
        float v = acc[nt][r2] + bv;
        v = v > 0.f ? v : 0.f;
        __builtin_nontemporal_store(v, &outbase[(size_t)node * 128 + n]);
      }
    }
  }
}

// ---------------------------------------------------------------------------
// Workspace layout (bytes):
//   cr_user @0 6400000 (8 replicas x 200000) | cr_item @6400000 3200000
//   row_user @9600000 800000 | row_item @10400000 400000
//   slots_user @10800000 2400000 | slots_item @13200000 2400000
//   srcs_user @15600000 2400000 | srcs_item @18000000 2400000
//   blks_user @20400000 1024 | blks_item @20401024 1024
//   Wp_user @20402048 65536 | Wp_item @20467584 65536
//   bias_user @20533120 512 | bias_item @20533632 512
//   xb_user @20534144 51200000 | xb_item @71734144 25600000 | end 97334144
// ---------------------------------------------------------------------------
extern "C" void kernel_launch(void* const* d_in, const int* in_sizes, int n_in,
                              void* d_out, int out_size, void* d_ws, size_t ws_size,
                              hipStream_t stream)
{
  const float* x_user = (const float*)d_in[0];
  const float* x_item = (const float*)d_in[1];
  const int* esrc_ui  = (const int*)d_in[2];
  const int* edst_ui  = (const int*)d_in[3];
  const int* esrc_iu  = (const int*)d_in[4];
  const int* edst_iu  = (const int*)d_in[5];
  const float* Wl_ui  = (const float*)d_in[6];
  const float* bl_ui  = (const float*)d_in[7];
  const float* Wr_ui  = (const float*)d_in[8];
  const float* Wl_iu  = (const float*)d_in[9];
  const float* bl_iu  = (const float*)d_in[10];
  const float* Wr_iu  = (const float*)d_in[11];
  const float* W_user = (const float*)d_in[12];
  const float* b_user = (const float*)d_in[13];
  const float* W_item = (const float*)d_in[14];
  const float* b_item = (const float*)d_in[15];
  float* out = (float*)d_out;

  char* ws = (char*)d_ws;
  int* cr_user    = (int*)(ws + 0);
  int* cr_item    = (int*)(ws + 6400000UL);
  int* row_user   = (int*)(ws + 9600000UL);
  int* row_item   = (int*)(ws + 10400000UL);
  int* slots_user = (int*)(ws + 10800000UL);
  int* slots_item = (int*)(ws + 13200000UL);
  int* srcs_user  = (int*)(ws + 15600000UL);
  int* srcs_item  = (int*)(ws + 18000000UL);
  int* blks_user  = (int*)(ws + 20400000UL);
  int* blks_item  = (int*)(ws + 20401024UL);
  unsigned short* Wp_user = (unsigned short*)(ws + 20402048UL);
  unsigned short* Wp_item = (unsigned short*)(ws + 20467584UL);
  float* bias_user = (float*)(ws + 20533120UL);
  float* bias_item = (float*)(ws + 20533632UL);
  unsigned short* xb_user = (unsigned short*)(ws + 20534144UL);
  unsigned short* xb_item = (unsigned short*)(ws + 71734144UL);

  const bool bf = ws_size >= 97334144UL;

  // zero the replicated counters (9.6 MB)
  (void)hipMemsetAsync(d_ws, 0, 9600000, stream);

  conv_weights<<<bf ? CW_END : CW_CVU, 256, 0, stream>>>(
      Wl_iu, Wr_iu, Wl_ui, Wr_ui, W_user, W_item, Wp_user, Wp_item,
      bl_iu, b_user, bl_ui, b_item, bias_user, bias_item,
      x_user, x_item, xb_user, xb_item);

  hist_slots<<<dim3(HB, 2), 256, 0, stream>>>(
      edst_iu, cr_user, slots_user, edst_ui, cr_item, slots_item);

  scan1<<<dim3(196, 2), 256, 0, stream>>>(cr_user, blks_user, cr_item, blks_item);
  scan3<<<dim3(196, 2), 256, 0, stream>>>(cr_user, blks_user, row_user,
                                          cr_item, blks_item, row_item);

  fill_ns<<<dim3(HB, 2), 256, 0, stream>>>(
      esrc_iu, edst_iu, slots_user, cr_user, srcs_user,
      esrc_ui, edst_ui, slots_item, cr_item, srcs_item);

  if (bf) {
    fused_gemm<true><<<NB_USER + NB_ITEM, 256, 0, stream>>>(
        xb_user, xb_item, row_user, srcs_user, Wp_user, bias_user,
        xb_item, xb_user, row_item, srcs_item, Wp_item, bias_item, out);
  } else {
    fused_gemm<false><<<NB_USER + NB_ITEM, 256, 0, stream>>>(
        x_user, x_item, row_user, srcs_user, Wp_user, bias_user,
        x_item, x_user, row_item, srcs_item, Wp_item, bias_item, out);
  }
}